// Round 1
// baseline (93.262 us; speedup 1.0000x reference)
//
#include <hip/hip_runtime.h>

#define BSZ  512
#define EPSF 1e-5f
#define NBLK 256          // 2 anchors per block; must be power of 2 for the ctr wrap trick
#define NTHR 512

// ws layout (floats): [0] uint block-completion counter (poison-tolerant: each
// launch adds exactly NBLK, so (old & (NBLK-1)) == NBLK-1 marks the last block
// for ANY initial value), [8 .. 8+3*512) per-anchor partials.
#define WS_PARTIAL 8

__device__ __forceinline__ float dist_xform(float v) {
    v = fmaxf(v, 0.0f);
    float z = (v == 0.0f) ? 1.0f : 0.0f;   // zmask per reference
    v = sqrtf(v + z * EPSF) + EPSF;
    return v * (1.0f - z);
}

// One fused kernel. Block b owns anchors a0=2b, a0+1.
// Phase 1: anchors + labels -> LDS.
// Phase 2: thread tid computes d^2[a][tid] for both anchors by streaming row
//          E[tid,:] (per-lane row stream; 64B lines L1-cached, E is L2-resident).
// Phase 3: per-anchor triplet sums fully in LDS (n == tid, so the negative-side
//          distance and label test are loop-invariant registers).
// Phase 4: last-done block (device-scope ctr) reduces the 512 per-anchor
//          partials and writes the two outputs.
__global__ __launch_bounds__(NTHR) void fused_kernel(const float* __restrict__ E,
                                                     const int* __restrict__ labels,
                                                     float* __restrict__ ws,
                                                     float* __restrict__ out) {
    __shared__ __align__(16) float ea0[BSZ];
    __shared__ __align__(16) float ea1[BSZ];
    __shared__ float drow[BSZ];
    __shared__ int   lab[BSZ];
    __shared__ int   poslist[BSZ];
    __shared__ int   npos_s;
    __shared__ float wsum[8];
    __shared__ int   wcnt[8];
    __shared__ float fs[4], fc[4], fv[4];
    __shared__ unsigned rank_s;

    const int tid = threadIdx.x;
    const int a0  = blockIdx.x * 2;
    float* partial = ws + WS_PARTIAL;

    // ---- Phase 1: stage anchors + labels (coalesced, 512 threads == 512 elems)
    lab[tid] = labels[tid];
    ea0[tid] = E[(size_t)a0 * BSZ + tid];
    ea1[tid] = E[(size_t)(a0 + 1) * BSZ + tid];
    __syncthreads();

    // ---- Phase 2: d^2 rows for both anchors; column j = tid.
    // Per-lane row stream: lane reads its own row E[tid,:]; each 64B line is
    // reused for 4 consecutive float4 iterations via L1. LDS reads of ea* are
    // wave-uniform broadcasts (conflict-free).
    float acc0a = 0.f, acc0b = 0.f, acc1a = 0.f, acc1b = 0.f;
    const float4* rj = (const float4*)(E + (size_t)tid * BSZ);
#pragma unroll 8
    for (int k4 = 0; k4 < BSZ / 4; ++k4) {
        const float4 x  = rj[k4];
        const float4 e0 = *(const float4*)&ea0[k4 * 4];
        const float4 e1 = *(const float4*)&ea1[k4 * 4];
        float d;
        d = x.x - e0.x; acc0a = fmaf(d, d, acc0a);
        d = x.y - e0.y; acc0b = fmaf(d, d, acc0b);
        d = x.z - e0.z; acc0a = fmaf(d, d, acc0a);
        d = x.w - e0.w; acc0b = fmaf(d, d, acc0b);
        d = x.x - e1.x; acc1a = fmaf(d, d, acc1a);
        d = x.y - e1.y; acc1b = fmaf(d, d, acc1b);
        d = x.z - e1.z; acc1a = fmaf(d, d, acc1a);
        d = x.w - e1.w; acc1b = fmaf(d, d, acc1b);
    }

    // ---- Phase 3: per-anchor triplet reduction (run twice, compile-time bodies)
    auto do_anchor = [&](int a, float acc) {
        if (tid == 0) npos_s = 0;
        drow[tid] = dist_xform(acc);          // j==a gives acc==0 -> drow 0 (zmask)
        __syncthreads();

        const int la = lab[a];
        if (lab[tid] == la && tid != a) poslist[atomicAdd(&npos_s, 1)] = tid;
        __syncthreads();

        const int   npos = npos_s;
        const float dn   = drow[tid];         // this thread's negative distance
        float sum = 0.f; int cnt = 0;
        if (lab[tid] != la) {                 // loop-invariant negative mask
            for (int m = 0; m < npos; ++m) {
                const float v = drow[poslist[m]] - dn;   // broadcast LDS reads
                if (v > 0.f)    sum += v;
                if (v > 1e-5f)  cnt++;
            }
        }
#pragma unroll
        for (int off = 32; off > 0; off >>= 1) {
            sum += __shfl_down(sum, off);
            cnt += __shfl_down(cnt, off);
        }
        const int wave = tid >> 6, lane = tid & 63;
        if (lane == 0) { wsum[wave] = sum; wcnt[wave] = cnt; }
        __syncthreads();
        if (tid == 0) {
            float S = 0.f; int C = 0;
#pragma unroll
            for (int w = 0; w < 8; ++w) { S += wsum[w]; C += wcnt[w]; }
            partial[a]            = S;
            partial[BSZ + a]      = (float)C;
            partial[2 * BSZ + a]  = (float)npos * (float)(BSZ - 1 - npos);
        }
        __syncthreads();   // protect wsum/drow/poslist reuse by the next anchor
    };
    do_anchor(a0,     acc0a + acc0b);
    do_anchor(a0 + 1, acc1a + acc1b);

    // ---- Phase 4: last-done block finalizes (device-scope release/acquire).
    // All global partial stores were made by tid 0, so tid 0's fence orders them.
    if (tid == 0) {
        __threadfence();                               // release partials
        rank_s = atomicAdd((unsigned*)ws, 1u);         // poison-tolerant mod trick
    }
    __syncthreads();
    if ((rank_s & (NBLK - 1)) == NBLK - 1) {
        __threadfence();                               // acquire others' partials
        if (tid < 256) {
            volatile const float* vp = partial;
            float s = vp[tid]           + vp[tid + 256];
            float c = vp[BSZ + tid]     + vp[BSZ + tid + 256];
            float v = vp[2*BSZ + tid]   + vp[2*BSZ + tid + 256];
#pragma unroll
            for (int off = 32; off > 0; off >>= 1) {
                s += __shfl_down(s, off);
                c += __shfl_down(c, off);
                v += __shfl_down(v, off);
            }
            const int wave = tid >> 6, lane = tid & 63;
            if (lane == 0) { fs[wave] = s; fc[wave] = c; fv[wave] = v; }
        }
        __syncthreads();
        if (tid == 0) {
            const float S = fs[0] + fs[1] + fs[2] + fs[3];
            const float C = fc[0] + fc[1] + fc[2] + fc[3];
            const float V = fv[0] + fv[1] + fv[2] + fv[3];
            out[0] = S / (C + 1e-5f);   // loss
            out[1] = C / (V + 1e-5f);   // fraction_positive
        }
    }
}

extern "C" void kernel_launch(void* const* d_in, const int* in_sizes, int n_in,
                              void* d_out, int out_size, void* d_ws, size_t ws_size,
                              hipStream_t stream) {
    const float* E      = (const float*)d_in[0];   // embeddings [512,512] fp32
    const int*   labels = (const int*)d_in[1];     // labels [512]
    float* out = (float*)d_out;
    float* ws  = (float*)d_ws;

    fused_kernel<<<NBLK, NTHR, 0, stream>>>(E, labels, ws, out);
}

// Round 3
// 84.997 us; speedup vs baseline: 1.0972x; 1.0972x over previous
//
#include <hip/hip_runtime.h>

#define BSZ 512
#define EPSF 1e-5f
#define KT   64          // k-chunk per block
#define NS   8           // split-k factor (NS*KT = 512)
#define TT   64          // square tile (rows = cols = 64)
#define LSTR 68          // LDS row stride: mult of 4 (16B-aligned b128), mod 32 = 4

// ws layout (floats): [0] completion counter (zeroed by dsq_kernel block 0 each
// launch; kernel boundary orders it -> old==NBLK2-1 provably marks last arrival),
// [8 .. 8+3*512) per-anchor partials, [2048 ..) P[NS][512][512] (8 MB)
#define WS_PARTIAL 8
#define WS_P       2048
#define NBLK2      512

__device__ __forceinline__ float dist_xform(float v) {
    v = fmaxf(v, 0.0f);
    float z = (v == 0.0f) ? 1.0f : 0.0f;   // zmask per reference
    v = sqrtf(v + z * EPSF) + EPSF;
    return v * (1.0f - z);
}

// ---- Kernel 1: partial squared distances. 64x64 tile, 4x4 micro, split-k. ----
// (round-0 proven: absmax 0.0, SQ_LDS_BANK_CONFLICT == 0)
// P[s][i][j] = sum_{k in chunk s} (E[i,k]-E[j,k])^2
// grid (8,8,8) = 512 blocks x 256 thr.  Also zeroes the ws[0] counter.
__global__ __launch_bounds__(256) void dsq_kernel(const float* __restrict__ E,
                                                  float* __restrict__ ws) {
    __shared__ __align__(16) float As[KT][LSTR];   // transposed: As[k][row]
    __shared__ __align__(16) float Bs[KT][LSTR];
    const int tid = threadIdx.x;
    const int bj = blockIdx.x * TT;
    const int bi = blockIdx.y * TT;
    const int k0 = blockIdx.z * KT;

    if (tid == 0 && blockIdx.x == 0 && blockIdx.y == 0 && blockIdx.z == 0)
        *(unsigned*)ws = 0u;   // poison-proof counter init for kernel 2

    // Stage transposed. Global float4 coalesced (16 thr x 16B = 256B rows).
    {
        const int r0 = tid >> 4;          // 0..15
        const int kc = (tid & 15) * 4;    // 0,4,..,60
#pragma unroll
        for (int p = 0; p < 4; ++p) {
            const int row = p * 16 + r0;
            float4 va = *(const float4*)(E + (size_t)(bi + row) * BSZ + k0 + kc);
            float4 vb = *(const float4*)(E + (size_t)(bj + row) * BSZ + k0 + kc);
            As[kc  ][row] = va.x; As[kc+1][row] = va.y; As[kc+2][row] = va.z; As[kc+3][row] = va.w;
            Bs[kc  ][row] = vb.x; Bs[kc+1][row] = vb.y; Bs[kc+2][row] = vb.z; Bs[kc+3][row] = vb.w;
        }
    }
    __syncthreads();

    const int tx = tid & 15;          // col group: j = bj + tx*4
    const int ty = tid >> 4;          // row group: i = bi + ty*4
    float acc[4][4];
#pragma unroll
    for (int r = 0; r < 4; ++r)
#pragma unroll
        for (int c = 0; c < 4; ++c) acc[r][c] = 0.0f;

#pragma unroll 8
    for (int kk = 0; kk < KT; ++kk) {
        // A: 4 addrs/wave (x16 broadcast), conflict-free. B: 2-way (free, m136).
        float4 A0 = *(const float4*)&As[kk][ty * 4];
        float4 B0 = *(const float4*)&Bs[kk][tx * 4];
        float ar[4] = {A0.x, A0.y, A0.z, A0.w};
        float br[4] = {B0.x, B0.y, B0.z, B0.w};
#pragma unroll
        for (int r = 0; r < 4; ++r)
#pragma unroll
            for (int c = 0; c < 4; ++c) {
                float d = ar[r] - br[c];
                acc[r][c] = fmaf(d, d, acc[r][c]);
            }
    }

    float* Pp = ws + WS_P + (size_t)blockIdx.z * BSZ * BSZ;
#pragma unroll
    for (int r = 0; r < 4; ++r) {   // 16 lanes x float4 = 256B contiguous per row
        float4 v = {acc[r][0], acc[r][1], acc[r][2], acc[r][3]};
        *(float4*)(Pp + (size_t)(bi + ty * 4 + r) * BSZ + bj + tx * 4) = v;
    }
}

// ---- Kernel 2: per-anchor triplet sums + last-block final reduce ----
// Body = round-0 triplet_kernel (proven); finalize = round-1 fence/atomic/volatile
// pattern (proven), with a provably-sound election (counter zeroed in kernel 1).
__global__ __launch_bounds__(256) void triplet_final_kernel(const int* __restrict__ labels,
                                                            float* __restrict__ ws,
                                                            float* __restrict__ out) {
    const int a = blockIdx.x;
    const int tid = threadIdx.x;
    __shared__ float drow[BSZ];
    __shared__ int   lab[BSZ];
    __shared__ int   poslist[BSZ];
    __shared__ int   npos_s;
    __shared__ float wsum[4];
    __shared__ int   wcnt[4];
    __shared__ float fs[4], fc[4], fv[4];
    __shared__ unsigned rank_s;

    float* partial = ws + WS_PARTIAL;

    if (tid == 0) npos_s = 0;
    for (int t = tid; t < BSZ; t += 256) lab[t] = labels[t];

    const float* P = ws + WS_P;
    {   // 256 threads x float2 = 512 cols; sum the NS chunk partials
        float2 s2 = {0.f, 0.f};
#pragma unroll
        for (int s = 0; s < NS; ++s) {
            float2 v = *(const float2*)(P + ((size_t)s * BSZ + a) * BSZ + tid * 2);
            s2.x += v.x; s2.y += v.y;
        }
        drow[tid * 2 + 0] = dist_xform(s2.x);
        drow[tid * 2 + 1] = dist_xform(s2.y);
    }
    __syncthreads();

    const int la = lab[a];
    for (int t = tid; t < BSZ; t += 256) {
        if (lab[t] == la && t != a) {
            int idx = atomicAdd(&npos_s, 1);
            poslist[idx] = t;
        }
    }
    __syncthreads();

    const int npos = npos_s;
    const int nneg = BSZ - 1 - npos;
    float sum = 0.0f;
    int   cnt = 0;
    const int total = npos * BSZ;
    for (int idx = tid; idx < total; idx += 256) {
        const int p = poslist[idx >> 9];   // broadcast within wave
        const int n = idx & (BSZ - 1);     // consecutive -> conflict-free
        if (lab[n] != la) {
            const float v = drow[p] - drow[n];   // margin = 0
            if (v > 0.0f)  sum += v;
            if (v > 1e-5f) cnt++;
        }
    }
#pragma unroll
    for (int off = 32; off > 0; off >>= 1) {
        sum += __shfl_down(sum, off);
        cnt += __shfl_down(cnt, off);
    }
    const int wave = tid >> 6, lane = tid & 63;
    if (lane == 0) { wsum[wave] = sum; wcnt[wave] = cnt; }
    __syncthreads();
    if (tid == 0) {
        partial[a]           = wsum[0] + wsum[1] + wsum[2] + wsum[3];
        partial[BSZ + a]     = (float)(wcnt[0] + wcnt[1] + wcnt[2] + wcnt[3]);
        partial[2*BSZ + a]   = (float)npos * (float)nneg;
    }

    // ---- election: counter starts at exactly 0 (zeroed by kernel 1), each of
    // the NBLK2 blocks adds 1 -> old == NBLK2-1 iff this is the LAST block, and
    // all other blocks' partial writes are ordered by their tid0 release fences.
    if (tid == 0) {
        __threadfence();                           // release this block's partials
        rank_s = atomicAdd((unsigned*)ws, 1u);
    }
    __syncthreads();
    if (rank_s == NBLK2 - 1) {
        __threadfence();                           // acquire others' partials
        volatile const float* vp = partial;
        float s = vp[tid]           + vp[tid + 256];
        float c = vp[BSZ + tid]     + vp[BSZ + tid + 256];
        float v = vp[2*BSZ + tid]   + vp[2*BSZ + tid + 256];
#pragma unroll
        for (int off = 32; off > 0; off >>= 1) {
            s += __shfl_down(s, off);
            c += __shfl_down(c, off);
            v += __shfl_down(v, off);
        }
        if (lane == 0) { fs[wave] = s; fc[wave] = c; fv[wave] = v; }
        __syncthreads();
        if (tid == 0) {
            const float S = fs[0] + fs[1] + fs[2] + fs[3];
            const float C = fc[0] + fc[1] + fc[2] + fc[3];
            const float V = fv[0] + fv[1] + fv[2] + fv[3];
            out[0] = S / (C + 1e-5f);   // loss
            out[1] = C / (V + 1e-5f);   // fraction_positive
        }
    }
}

extern "C" void kernel_launch(void* const* d_in, const int* in_sizes, int n_in,
                              void* d_out, int out_size, void* d_ws, size_t ws_size,
                              hipStream_t stream) {
    const float* E      = (const float*)d_in[0];   // embeddings [512,512] fp32
    const int*   labels = (const int*)d_in[1];     // labels [512]
    float* out = (float*)d_out;
    float* ws  = (float*)d_ws;

    dsq_kernel<<<dim3(8, 8, NS), 256, 0, stream>>>(E, ws);
    triplet_final_kernel<<<NBLK2, 256, 0, stream>>>(labels, ws, out);
}